// Round 11
// baseline (363.538 us; speedup 1.0000x reference)
//
#include <hip/hip_runtime.h>
#include <hip/hip_bf16.h>

// Swin window MHSA, MI355X, round 11.
//   k_pc2  : prep (Aext/Wov3/cvec/relL2, 16-col tiles) + conv (X -> Xroll)
//   k_attn5: per (n,window): M_h = G_h^T.Xp (MFMA, LDS) -> S -> softmax ->
//            T -> Y += Wov.T. No M workspace; gemm1 deleted.

#define NBATCH 8
#define TROWS  3200           // padded token rows

typedef unsigned short ushort_t;
typedef __attribute__((ext_vector_type(8))) short bf16x8;   // 8 bf16 = 4 VGPR
typedef __attribute__((ext_vector_type(8))) unsigned short u16x8;
typedef __attribute__((ext_vector_type(4))) float f32x4;    // MFMA acc

__device__ __forceinline__ float b2f(ushort_t u) {
  union { unsigned int i; float f; } v; v.i = ((unsigned int)u) << 16; return v.f;
}
__device__ __forceinline__ ushort_t f2b(float f) {
  union { float f; unsigned int u; } v; v.f = f;
  unsigned int u = v.u;
  return (ushort_t)((u + 0x7FFFu + ((u >> 16) & 1u)) >> 16);
}
__device__ __forceinline__ int regof(int y) { return (y < 49) ? 0 : ((y < 53) ? 1 : 2); }
__device__ __forceinline__ int div7(int t) { return (t * 37) >> 8; }  // t/7, t<64
__device__ __forceinline__ int tmap(int p, int gi, int gj) {
  int wi = div7(p); return (gi * 7 + wi) * 56 + gj * 7 + (p - wi * 7);
}
__device__ __forceinline__ ushort4 pack4(f32x4 a) {
  ushort4 u; u.x = f2b(a[0]); u.y = f2b(a[1]); u.z = f2b(a[2]); u.w = f2b(a[3]);
  return u;
}

// ================= merged prep + conv, 16-col tiles =================
// blocks 0..127   : Aext[h*256+a][b0..b0+15] (h=blk>>4, b0=(blk&15)*16)
// blocks 128..255 : Wov3[o0..o0+15][h*256+d]
// blocks 256..263 : w1/w2 rows of Aext (rows 2048+h / 2056+h)
// block  264      : zero Aext rows 2064..2175
// blocks 265..520 : cvec
// block  521      : relL2 (+c0/16)
// blocks 522..977 : conv (X -> Xroll)
__global__ void k_pc2(const float* __restrict__ Wk, const float* __restrict__ Wq,
                      const float* __restrict__ Wo, const float* __restrict__ Wv,
                      const float* __restrict__ bk, const float* __restrict__ bq,
                      const float* __restrict__ bv, const float* __restrict__ bo,
                      const float* __restrict__ relc, const float* __restrict__ X,
                      ushort_t* __restrict__ Aext, ushort_t* __restrict__ Wov3,
                      float* __restrict__ cvec, float* __restrict__ relL2,
                      ushort_t* __restrict__ Xroll) {
  __shared__ float red[8];
  int blk = blockIdx.x, t = threadIdx.x;
  if (blk >= 522) {
    // ---- conv ----
    const int cb = blk - 522;
    const int n = cb / 57, y = cb % 57;
    ushort_t* xr = Xroll + (size_t)n * TROWS * 256;
    const int d = t;
    if (y == 56) {
      for (int i = d; i < 64 * 256 / 8; i += 256)
        *(u16x8*)(xr + 3136 * 256 + i * 8) = (u16x8){0,0,0,0,0,0,0,0};
      return;
    }
    const int c = d >> 4, p1 = (d >> 2) & 3, p2 = d & 3;
    const int sp = c * 16 + (((p1 + 1) & 3) << 2) + ((p2 + 1) & 3);
    const int ty = (p1 == 3) ? y : ((y == 0) ? 55 : y - 1);
    const float* rowp = X + (size_t)n * 256 * 3136 + sp * 3136 + ty * 56;
    ushort_t* orow = xr + y * 56 * 256 + d;
    for (int x = 0; x < 56; ++x) {
      int tx = (p2 == 3) ? x : ((x == 0) ? 55 : x - 1);
      orow[x * 256] = f2b(rowp[tx]);
    }
  } else if (blk < 128) {
    // ---- Aext G: 16 b-cols per block ----
    const int h = blk >> 4, b0 = (blk & 15) << 4, a = t;
    const float* wkh = Wk + h * 65536;
    const float* wqh = Wq + h * 65536 + b0;
    float acc[16];
#pragma unroll
    for (int j = 0; j < 16; ++j) acc[j] = 0.f;
    for (int dd = 0; dd < 256; ++dd) {
      float wk = wkh[dd * 256 + a];
#pragma unroll
      for (int j = 0; j < 16; ++j) acc[j] += wk * wqh[dd * 256 + j];
    }
    ushort_t* dst = Aext + (h * 256 + a) * 256 + b0;
#pragma unroll
    for (int j = 0; j < 16; ++j) dst[j] = f2b(acc[j]);
  } else if (blk < 256) {
    // ---- Wov3: 16 o-rows per block ----
    const int bb = blk - 128;
    const int h = bb >> 4, o0 = (bb & 15) << 4, d = t;
    float acc[16];
#pragma unroll
    for (int j = 0; j < 16; ++j) acc[j] = 0.f;
    for (int dd = 0; dd < 256; ++dd) {
      float wv = Wv[(h * 256 + dd) * 256 + d];
#pragma unroll
      for (int j = 0; j < 16; ++j) acc[j] += Wo[(o0 + j) * 2048 + h * 256 + dd] * wv;
    }
#pragma unroll
    for (int j = 0; j < 16; ++j)
      Wov3[(o0 + j) * 2048 + h * 256 + d] = f2b(acc[j]);
  } else if (blk < 264) {
    const int h = blk - 256;
    float s1 = 0.f, s2 = 0.f;
    for (int dd = 0; dd < 256; ++dd) {
      s1 += bk[h * 256 + dd] * Wq[(h * 256 + dd) * 256 + t];
      s2 += bq[h * 256 + dd] * Wk[(h * 256 + dd) * 256 + t];
    }
    Aext[(2048 + h) * 256 + t] = f2b(s1);
    Aext[(2056 + h) * 256 + t] = f2b(s2);
  } else if (blk == 264) {
    for (int i = t; i < 112 * 256 / 8; i += 256)
      *(u16x8*)(Aext + 2064 * 256 + i * 8) = (u16x8){0,0,0,0,0,0,0,0};
  } else if (blk < 521) {
    const int o = blk - 265;
    const float* wob = Wo + o * 2048;
    float acc = 0.f;
#pragma unroll
    for (int j = 0; j < 8; ++j) acc += wob[j * 256 + t] * bv[j * 256 + t];
#pragma unroll
    for (int s = 1; s < 64; s <<= 1) acc += __shfl_xor(acc, s);
    if ((t & 63) == 0) red[t >> 6] = acc;
    __syncthreads();
    if (t == 0) cvec[o] = bo[o] + red[0] + red[1] + red[2] + red[3];
  } else {
    if (t < 8) {
      float c = 0.f;
      for (int dd = 0; dd < 256; ++dd) c += bk[t * 256 + dd] * bq[t * 256 + dd];
      red[t] = c * 0.0625f;
    }
    __syncthreads();
    for (int i = t; i < 8 * 169; i += 256) {
      int h = i / 169, idx = i - h * 169;
      relL2[i] = relc[idx * 8 + h] + red[h];
    }
  }
}

// ================= attn5: M(MFMA) -> S -> softmax -> T -> P4 ==============
#define XP3 264
__global__ __launch_bounds__(512, 4) void k_attn5(
    const ushort_t* __restrict__ Xroll, const ushort_t* __restrict__ Aext,
    const ushort_t* __restrict__ Wov3, const float* __restrict__ relL2,
    const float* __restrict__ cvec, float* __restrict__ out) {
  __shared__ ushort_t Xp[64 * XP3];   // [p][d]          33792 B
  __shared__ ushort_t Ms[64 * XP3];   // M^T[q][a]; TT aliases after S  33792 B
  __shared__ ushort_t StB[64 * 72];   //                  9216 B
  __shared__ float aqsL[8 * 64];
  __shared__ float bpsL[8 * 64];      // total 80896 B -> 2 blocks/CU

  const int tid = threadIdx.x;
  const int wave = tid >> 6, lane = tid & 63;
  const int quad = lane >> 4, l16 = lane & 15;
  const int n = blockIdx.x >> 6, g = blockIdx.x & 63;
  const int gi = g >> 3, gj = g & 7;
  const ushort_t* Xn = Xroll + (size_t)n * TROWS * 256;

  // ---- prologue: Xp gather ----
  {
    const int p = tid & 63, cg = tid >> 6;
    if (p < 49) {
      int t = tmap(p, gi, gj);
#pragma unroll
      for (int i = 0; i < 4; ++i)
        *(u16x8*)(&Xp[p * XP3 + (cg * 4 + i) * 8]) =
            *(const u16x8*)(Xn + t * 256 + (cg * 4 + i) * 8);
    } else {
#pragma unroll
      for (int i = 0; i < 4; ++i)
        *(u16x8*)(&Xp[p * XP3 + (cg * 4 + i) * 8]) = (u16x8){0,0,0,0,0,0,0,0};
    }
  }
  __syncthreads();

  // ---- bias MFMA: rows 2048..2063 of Aext x Xp -> aq/bp all heads ----
  if (wave < 4) {
    f32x4 bacc = (f32x4){0.f, 0.f, 0.f, 0.f};
#pragma unroll
    for (int kk = 0; kk < 8; ++kk) {
      bf16x8 af = *(const bf16x8*)(Aext + (2048 + l16) * 256 + kk * 32 + quad * 8);
      bf16x8 bf = *(const bf16x8*)(&Xp[(wave * 16 + l16) * XP3 + kk * 32 + quad * 8]);
      bacc = __builtin_amdgcn_mfma_f32_16x16x32_bf16(af, bf, bacc, 0, 0, 0);
    }
#pragma unroll
    for (int r = 0; r < 4; ++r) {
      int row = quad * 4 + r;
      if (row < 8) aqsL[row * 64 + wave * 16 + l16] = bacc[r];
      else         bpsL[(row - 8) * 64 + wave * 16 + l16] = bacc[r];
    }
  }

  // ---- phase-T A-frags: X^T[d][p], d-tiles {2w,2w+1}, in registers ----
  bf16x8 xfr[2][2];
#pragma unroll
  for (int i = 0; i < 2; ++i) {
    const int d = (wave * 2 + i) * 16 + l16;
#pragma unroll
    for (int kk = 0; kk < 2; ++kk)
#pragma unroll
      for (int j = 0; j < 8; ++j)
        xfr[i][kk][j] = (short)Xp[(kk * 32 + quad * 8 + j) * XP3 + d];
  }

  // S-phase per-lane constants
  const int qt = wave >> 1, ph = wave & 1;
  const int q = qt * 16 + l16;
  const int qq = (q < 49) ? q : 48;
  const int yq = div7(qq), xq = qq - yq * 7;
  const int fq = regof(gi * 7 + yq) * 3 + regof(gj * 7 + xq);

  f32x4 yac[2][4];
#pragma unroll
  for (int i = 0; i < 2; ++i)
#pragma unroll
    for (int j = 0; j < 4; ++j) yac[i][j] = (f32x4){0.f, 0.f, 0.f, 0.f};

  for (int h = 0; h < 8; ++h) {
    __syncthreads();  // b0: Ms/TT free (prev P4 done); bias ready (h=0)

    // ---- M-phase: Ms[q][a] = (G_h^T Xp), a-tiles {2w,2w+1} x 4 q-tiles ----
    {
      const ushort_t* gh = Aext + h * 65536;
      f32x4 macc[2][4];
#pragma unroll
      for (int i = 0; i < 2; ++i)
#pragma unroll
        for (int j = 0; j < 4; ++j) macc[i][j] = (f32x4){0.f, 0.f, 0.f, 0.f};
#pragma unroll
      for (int kk = 0; kk < 8; ++kk) {
        bf16x8 af[2], bf[4];
#pragma unroll
        for (int i = 0; i < 2; ++i)
          af[i] = *(const bf16x8*)(gh + ((wave * 2 + i) * 16 + l16) * 256 + kk * 32 + quad * 8);
#pragma unroll
        for (int j = 0; j < 4; ++j)
          bf[j] = *(const bf16x8*)(&Xp[(j * 16 + l16) * XP3 + kk * 32 + quad * 8]);
#pragma unroll
        for (int i = 0; i < 2; ++i)
#pragma unroll
          for (int j = 0; j < 4; ++j)
            macc[i][j] = __builtin_amdgcn_mfma_f32_16x16x32_bf16(af[i], bf[j], macc[i][j], 0, 0, 0);
      }
#pragma unroll
      for (int i = 0; i < 2; ++i)
#pragma unroll
        for (int j = 0; j < 4; ++j)
          *(ushort4*)(&Ms[(j * 16 + l16) * XP3 + (wave * 2 + i) * 16 + quad * 4]) =
              pack4(macc[i][j]);
    }
    __syncthreads();  // b1: Ms ready

    // ---- S: A = Xp p-tiles, B = Ms row q (LDS) ----
    f32x4 sacc[2];
#pragma unroll
    for (int i = 0; i < 2; ++i) sacc[i] = (f32x4){0.f, 0.f, 0.f, 0.f};
#pragma unroll
    for (int kk = 0; kk < 8; ++kk) {
      bf16x8 bm = *(const bf16x8*)(&Ms[q * XP3 + kk * 32 + quad * 8]);
#pragma unroll
      for (int i = 0; i < 2; ++i) {
        bf16x8 af = *(const bf16x8*)(&Xp[((ph * 2 + i) * 16 + l16) * XP3 + kk * 32 + quad * 8]);
        sacc[i] = __builtin_amdgcn_mfma_f32_16x16x32_bf16(af, bm, sacc[i], 0, 0, 0);
      }
    }
    {
      const float aqv = aqsL[h * 64 + q];
      const float* relh = relL2 + h * 169;
#pragma unroll
      for (int i = 0; i < 2; ++i) {
        ushort4 sv;
        ushort_t* svp = &sv.x;
#pragma unroll
        for (int r = 0; r < 4; ++r) {
          int p = (ph * 2 + i) * 16 + quad * 4 + r;
          float val = -1e30f;
          if (p < 49) {
            int yp = div7(p), xp = p - yp * 7;
            int fp = regof(gi * 7 + yp) * 3 + regof(gj * 7 + xp);
            val = (sacc[i][r] + aqv + bpsL[h * 64 + p]) * 0.0625f +
                  relh[(yp - yq + 6) + 13 * (xp - xq + 6)];
            if (fp != fq) val -= 100.f;
          }
          svp[r] = f2b(val);
        }
        *(ushort4*)(&StB[q * 72 + (ph * 2 + i) * 16 + quad * 4]) = sv;
      }
    }
    __syncthreads();  // b2: StB scores complete

    // ---- softmax over p per row q, in-place bf16 ----
    {
      const int sq = tid >> 3, sub = tid & 7;
      ushort_t* row = &StB[sq * 72 + sub * 8];
      bf16x8 in8 = *(const bf16x8*)row;
      float v[8];
#pragma unroll
      for (int i = 0; i < 8; ++i) v[i] = b2f((ushort_t)in8[i]);
      float m = v[0];
#pragma unroll
      for (int i = 1; i < 8; ++i) m = fmaxf(m, v[i]);
      m = fmaxf(m, __shfl_xor(m, 1));
      m = fmaxf(m, __shfl_xor(m, 2));
      m = fmaxf(m, __shfl_xor(m, 4));
      float s = 0.f;
#pragma unroll
      for (int i = 0; i < 8; ++i) { v[i] = __expf(v[i] - m); s += v[i]; }
      s += __shfl_xor(s, 1);
      s += __shfl_xor(s, 2);
      s += __shfl_xor(s, 4);
      float inv = 1.f / s;
      bf16x8 w8;
#pragma unroll
      for (int i = 0; i < 8; ++i) w8[i] = (short)f2b(v[i] * inv);
      *(bf16x8*)row = w8;
    }
    __syncthreads();  // b3: wmap^T ready (Ms reads all done -> TT may overwrite)

    // ---- T: TT[q][d] = (X wmap)[d][q]  (TT aliases Ms) ----
    {
      f32x4 tacc[2][4];
#pragma unroll
      for (int i = 0; i < 2; ++i)
#pragma unroll
        for (int j = 0; j < 4; ++j) tacc[i][j] = (f32x4){0.f, 0.f, 0.f, 0.f};
#pragma unroll
      for (int kk = 0; kk < 2; ++kk) {
        bf16x8 bw[4];
#pragma unroll
        for (int j = 0; j < 4; ++j)
          bw[j] = *(const bf16x8*)(&StB[(j * 16 + l16) * 72 + kk * 32 + quad * 8]);
#pragma unroll
        for (int i = 0; i < 2; ++i)
#pragma unroll
          for (int j = 0; j < 4; ++j)
            tacc[i][j] = __builtin_amdgcn_mfma_f32_16x16x32_bf16(xfr[i][kk], bw[j], tacc[i][j], 0, 0, 0);
      }
#pragma unroll
      for (int i = 0; i < 2; ++i)
#pragma unroll
        for (int j = 0; j < 4; ++j)
          *(ushort4*)(&Ms[(j * 16 + l16) * XP3 + (wave * 2 + i) * 16 + quad * 4]) =
              pack4(tacc[i][j]);
    }
    __syncthreads();  // b4: TT ready

    // ---- P4: yac[o][q] += TT . Wov_h ----
    {
      const ushort_t* wb = Wov3 + h * 256 + quad * 8;
#pragma unroll
      for (int kk = 0; kk < 8; ++kk) {
        bf16x8 at[4];
#pragma unroll
        for (int j = 0; j < 4; ++j)
          at[j] = *(const bf16x8*)(&Ms[(j * 16 + l16) * XP3 + kk * 32 + quad * 8]);
#pragma unroll
        for (int i = 0; i < 2; ++i) {
          bf16x8 bwv = *(const bf16x8*)(wb + (size_t)((wave * 2 + i) * 16 + l16) * 2048 + kk * 32);
#pragma unroll
          for (int j = 0; j < 4; ++j)
            yac[i][j] = __builtin_amdgcn_mfma_f32_16x16x32_bf16(at[j], bwv, yac[i][j], 0, 0, 0);
        }
      }
    }
  }

  // ---- epilogue ----
  float* obase = out + (size_t)n * 256 * 3136;
#pragma unroll
  for (int i = 0; i < 2; ++i) {
    const int o = (wave * 2 + i) * 16 + l16;
    const float cv = cvec[o];
#pragma unroll
    for (int j = 0; j < 4; ++j) {
#pragma unroll
      for (int r = 0; r < 4; ++r) {
        int qv = j * 16 + quad * 4 + r;
        if (qv < 49) {
          int pos = tmap(qv, gi, gj);
          obase[(size_t)o * 3136 + pos] = yac[i][j][r] + cv;
        }
      }
    }
  }
}

extern "C" void kernel_launch(void* const* d_in, const int* in_sizes, int n_in,
                              void* d_out, int out_size, void* d_ws, size_t ws_size,
                              hipStream_t stream) {
  (void)in_sizes; (void)n_in; (void)out_size; (void)ws_size;
  const float* X  = (const float*)d_in[0];
  const float* Wk = (const float*)d_in[1];
  const float* bk = (const float*)d_in[2];
  const float* Wq = (const float*)d_in[3];
  const float* bq = (const float*)d_in[4];
  const float* Wv = (const float*)d_in[5];
  const float* bv = (const float*)d_in[6];
  const float* Wo = (const float*)d_in[7];
  const float* bo = (const float*)d_in[8];
  const float* rc = (const float*)d_in[9];

  ushort_t* Xroll = (ushort_t*)d_ws;                 // 8*3200*256 u16
  ushort_t* Aext  = Xroll + (size_t)8 * TROWS * 256; // 2176*256 u16
  ushort_t* Wov3  = Aext + 2176 * 256;               // 256*2048 u16
  float* fbase = (float*)(Wov3 + 256 * 2048);
  float* cvec  = fbase;         // 256 f32
  float* relL2 = fbase + 256;   // 8*169 f32
  float* out = (float*)d_out;

  k_pc2  <<<dim3(978), dim3(256), 0, stream>>>(Wk, Wq, Wo, Wv, bk, bq, bv, bo, rc, X,
                                               Aext, Wov3, cvec, relL2, Xroll);
  k_attn5<<<dim3(NBATCH * 64), dim3(512), 0, stream>>>(Xroll, Aext, Wov3, relL2, cvec, out);
}